// Round 1
// baseline (493.025 us; speedup 1.0000x reference)
//
#include <hip/hip_runtime.h>

// Shapes fixed by the reference: (B=8, C=8, H=1024, W=1024) fp32, two images.
constexpr int B = 8, C = 8;
constexpr long long PLANE = 1024LL * 1024LL;          // H*W floats per (b,c) plane
constexpr long long NCHW  = (long long)C * PLANE;     // 8,388,608 per-batch elements
constexpr int BLOCKS_PER_PLANE = 16;                  // 2*64 planes * 16 = 2048 blocks
constexpr int NBLOCKS = 2 * B * C * BLOCKS_PER_PLANE; // 2048
constexpr int THREADS = 256;
constexpr int F4_PER_PLANE = (int)(PLANE / 4);                     // 262144 float4/plane
constexpr int ITERS = F4_PER_PLANE / (BLOCKS_PER_PLANE * THREADS); // 64
constexpr int STRIDE_F4 = BLOCKS_PER_PLANE * THREADS;              // 4096 float4 = 64 KiB

typedef float f32x4 __attribute__((ext_vector_type(4)));

// Per-block partials: part[gb] = {sum(x), sum(x^2)} over the block's share of
// one (img,b,c) plane. Blocks sharing a plane interleave at 4 KiB granularity
// (block-cyclic), so the 16 co-resident blocks of a plane form ONE advancing
// contiguous read front (128 fronts chip-wide) instead of 2048 disjoint
// 256 KiB streams -> better DRAM row locality.
// Every slot is written unconditionally -> no zero-init of d_ws needed.
__global__ __launch_bounds__(THREADS) void moments_pass1(
    const float* __restrict__ img0, const float* __restrict__ img1,
    double2* __restrict__ part) {
  int gb    = blockIdx.x;                 // 0..2047
  int plane = gb / BLOCKS_PER_PLANE;      // 0..127  (imgi*64 + b*8 + c)
  int chunk = gb % BLOCKS_PER_PLANE;      // 0..15
  int imgi  = plane >> 6;
  int rem   = plane & 63;
  int tid   = threadIdx.x;

  const float* plane_base = (imgi ? img1 : img0) + (long long)rem * PLANE;
  // block-cyclic: this block's lane tid reads f32x4 index
  //   chunk*THREADS + tid + it*STRIDE_F4   (4 KiB granularity interleave)
  const f32x4* p = (const f32x4*)plane_base + (long long)chunk * THREADS + tid;

  double s1a = 0.0, s1b = 0.0;
  double q0 = 0.0, q1 = 0.0, q2 = 0.0, q3 = 0.0;
#pragma unroll 8
  for (int it = 0; it < ITERS; ++it) {
    f32x4 v = __builtin_nontemporal_load(p + (long long)it * STRIDE_F4);
    double a = (double)v.x, b2 = (double)v.y, c2 = (double)v.z, d = (double)v.w;
    s1a += a + b2;
    s1b += c2 + d;
    q0 = fma(a, a, q0);
    q1 = fma(b2, b2, q1);
    q2 = fma(c2, c2, q2);
    q3 = fma(d, d, q3);
  }
  double s1 = s1a + s1b;
  double s2 = (q0 + q1) + (q2 + q3);

  // wave-64 shuffle tree
  for (int off = 32; off > 0; off >>= 1) {
    s1 += __shfl_down(s1, off, 64);
    s2 += __shfl_down(s2, off, 64);
  }

  __shared__ double sh1[4], sh2[4];
  int wave = tid >> 6, lane = tid & 63;
  if (lane == 0) { sh1[wave] = s1; sh2[wave] = s2; }
  __syncthreads();
  if (tid == 0) {
    double t1 = (sh1[0] + sh1[1]) + (sh1[2] + sh1[3]);
    double t2 = (sh2[0] + sh2[1]) + (sh2[2] + sh2[3]);
    part[gb] = make_double2(t1, t2);
  }
}

// One block, 16 waves; wave w = (imgi*8 + b). Group's 128 partials are
// contiguous at part[w*128 .. w*128+127] (8 c-planes x 16 chunks).
__global__ __launch_bounds__(1024) void moments_pass2(
    const double2* __restrict__ part, float* __restrict__ out) {
  int tid  = threadIdx.x;
  int w    = tid >> 6;          // 0..15
  int lane = tid & 63;
  int b    = w & 7;

  const double2 p0 = part[w * 128 + lane];
  const double2 p1 = part[w * 128 + 64 + lane];
  int c0 = lane >> 4;           // 0..3
  int c1 = c0 + 4;              // 4..7

  double s1 = p0.x + p1.x;
  double s2 = p0.y + p1.y;
  double d1 = (c0 == b ? p0.x : 0.0) + (c1 == b ? p1.x : 0.0);
  double d2 = (c0 == b ? p0.y : 0.0) + (c1 == b ? p1.y : 0.0);

  for (int off = 32; off > 0; off >>= 1) {
    s1 += __shfl_down(s1, off, 64);
    s2 += __shfl_down(s2, off, 64);
    d1 += __shfl_down(d1, off, 64);
    d2 += __shfl_down(d2, off, 64);
  }

  __shared__ double msh[16];
  if (lane == 0) {
    const double N    = (double)NCHW;      // 8388608
    const double Npix = (double)PLANE;     // 1048576
    const double denom = N * N;            // (C*H*W)^2, ORDER=2
    double mean = s1 / N;
    double var  = (s2 - s1 * s1 / N) / (N - 1.0);   // unbiased (ddof=1)
    double ssq  = d2 - 2.0 * mean * d1 + Npix * mean * mean;
    msh[w] = ssq / var / denom;
  }
  __syncthreads();
  if (tid == 0) {
    double m0 = 0.0, m1 = 0.0;
    for (int i = 0; i < 8; ++i)  m0 += msh[i];
    for (int i = 8; i < 16; ++i) m1 += msh[i];
    out[0] = (float)fabs(m0 - m1);
  }
}

extern "C" void kernel_launch(void* const* d_in, const int* in_sizes, int n_in,
                              void* d_out, int out_size, void* d_ws, size_t ws_size,
                              hipStream_t stream) {
  const float* img0 = (const float*)d_in[0];
  const float* img1 = (const float*)d_in[1];
  double2* part = (double2*)d_ws;   // 2048 * 16 B = 32 KiB, fully overwritten
  moments_pass1<<<NBLOCKS, THREADS, 0, stream>>>(img0, img1, part);
  moments_pass2<<<1, 1024, 0, stream>>>(part, (float*)d_out);
}

// Round 2
// 468.740 us; speedup vs baseline: 1.0518x; 1.0518x over previous
//
#include <hip/hip_runtime.h>

// Shapes fixed by the reference: (B=8, C=8, H=1024, W=1024) fp32, two images.
constexpr int B = 8, C = 8;
constexpr long long PLANE = 1024LL * 1024LL;          // H*W floats per (b,c) plane
constexpr long long NCHW  = (long long)C * PLANE;     // 8,388,608 per-batch elements
// R2: fewer, longer sequential streams. 512 blocks * 1 MiB contiguous each
// (R0: 2048 x 256 KiB = 3.8 TB/s; R1: 4 KiB-cyclic = 3.2 TB/s, worse).
// Harness fill hits 6.7 TB/s with ~800 streams -> move toward that regime.
constexpr int BLOCKS_PER_PLANE = 4;                   // 2*64 planes * 4 = 512 blocks
constexpr int NBLOCKS = 2 * B * C * BLOCKS_PER_PLANE; // 512
constexpr int THREADS = 256;
constexpr int F4_PER_BLOCK = (int)(PLANE / BLOCKS_PER_PLANE / 4); // 65536 float4
constexpr int ITERS = F4_PER_BLOCK / THREADS;                      // 256
constexpr int PART_PER_GROUP = C * BLOCKS_PER_PLANE;               // 32 per (img,b)

typedef float f32x4 __attribute__((ext_vector_type(4)));

// Per-block partials: part[gb] = {sum(x), sum(x^2)} over the block's private
// contiguous 1 MiB chunk of one (img,b,c) plane. Every slot is written
// unconditionally -> no zero-init of d_ws needed.
__global__ __launch_bounds__(THREADS) void moments_pass1(
    const float* __restrict__ img0, const float* __restrict__ img1,
    double2* __restrict__ part) {
  int gb    = blockIdx.x;                 // 0..511
  int plane = gb / BLOCKS_PER_PLANE;      // 0..127  (imgi*64 + b*8 + c)
  int chunk = gb % BLOCKS_PER_PLANE;      // 0..3
  int imgi  = plane >> 6;
  int rem   = plane & 63;
  int tid   = threadIdx.x;

  const float* base = (imgi ? img1 : img0)
                    + (long long)rem * PLANE
                    + (long long)chunk * (PLANE / BLOCKS_PER_PLANE);
  const f32x4* p = (const f32x4*)base;

  double s1a = 0.0, s1b = 0.0;
  double q0 = 0.0, q1 = 0.0, q2 = 0.0, q3 = 0.0;
#pragma unroll 8
  for (int it = 0; it < ITERS; ++it) {
    f32x4 v = __builtin_nontemporal_load(p + it * THREADS + tid);
    double a = (double)v.x, b2 = (double)v.y, c2 = (double)v.z, d = (double)v.w;
    s1a += a + b2;
    s1b += c2 + d;
    q0 = fma(a, a, q0);
    q1 = fma(b2, b2, q1);
    q2 = fma(c2, c2, q2);
    q3 = fma(d, d, q3);
  }
  double s1 = s1a + s1b;
  double s2 = (q0 + q1) + (q2 + q3);

  // wave-64 shuffle tree
  for (int off = 32; off > 0; off >>= 1) {
    s1 += __shfl_down(s1, off, 64);
    s2 += __shfl_down(s2, off, 64);
  }

  __shared__ double sh1[4], sh2[4];
  int wave = tid >> 6, lane = tid & 63;
  if (lane == 0) { sh1[wave] = s1; sh2[wave] = s2; }
  __syncthreads();
  if (tid == 0) {
    double t1 = (sh1[0] + sh1[1]) + (sh1[2] + sh1[3]);
    double t2 = (sh2[0] + sh2[1]) + (sh2[2] + sh2[3]);
    part[gb] = make_double2(t1, t2);
  }
}

// One block, 16 waves; wave w = (imgi*8 + b). Group's 32 partials are
// contiguous at part[w*32 .. w*32+31] (8 c-planes x 4 chunks, c = idx>>2).
__global__ __launch_bounds__(1024) void moments_pass2(
    const double2* __restrict__ part, float* __restrict__ out) {
  int tid  = threadIdx.x;
  int w    = tid >> 6;          // 0..15
  int lane = tid & 63;
  int b    = w & 7;

  double s1 = 0.0, s2 = 0.0, d1 = 0.0, d2 = 0.0;
  if (lane < PART_PER_GROUP) {
    const double2 p0 = part[w * PART_PER_GROUP + lane];
    int c = lane >> 2;          // 0..7
    s1 = p0.x;
    s2 = p0.y;
    if (c == b) { d1 = p0.x; d2 = p0.y; }
  }

  for (int off = 32; off > 0; off >>= 1) {
    s1 += __shfl_down(s1, off, 64);
    s2 += __shfl_down(s2, off, 64);
    d1 += __shfl_down(d1, off, 64);
    d2 += __shfl_down(d2, off, 64);
  }

  __shared__ double msh[16];
  if (lane == 0) {
    const double N    = (double)NCHW;      // 8388608
    const double Npix = (double)PLANE;     // 1048576
    const double denom = N * N;            // (C*H*W)^2, ORDER=2
    double mean = s1 / N;
    double var  = (s2 - s1 * s1 / N) / (N - 1.0);   // unbiased (ddof=1)
    double ssq  = d2 - 2.0 * mean * d1 + Npix * mean * mean;
    msh[w] = ssq / var / denom;
  }
  __syncthreads();
  if (tid == 0) {
    double m0 = 0.0, m1 = 0.0;
    for (int i = 0; i < 8; ++i)  m0 += msh[i];
    for (int i = 8; i < 16; ++i) m1 += msh[i];
    out[0] = (float)fabs(m0 - m1);
  }
}

extern "C" void kernel_launch(void* const* d_in, const int* in_sizes, int n_in,
                              void* d_out, int out_size, void* d_ws, size_t ws_size,
                              hipStream_t stream) {
  const float* img0 = (const float*)d_in[0];
  const float* img1 = (const float*)d_in[1];
  double2* part = (double2*)d_ws;   // 512 * 16 B = 8 KiB, fully overwritten
  moments_pass1<<<NBLOCKS, THREADS, 0, stream>>>(img0, img1, part);
  moments_pass2<<<1, 1024, 0, stream>>>(part, (float*)d_out);
}